// Round 3
// baseline (17705.251 us; speedup 1.0000x reference)
//
#include <hip/hip_runtime.h>
#include <hip/hip_bf16.h>

// GRU forward. B=128, S=1024, I=256, H=512.
// d_in: inputs f32 [128][1024][256], W_in f32 [256][1536], W_h f32 [512][1536],
//       bias f32 [3072] (b_in | b_h)
// d_out: hidden_sequence f32 [128][1024][512] then h_last f32 [128][512]
//
// Phase 1: x_proj = inputs@W_in + b_in, fp32 GEMM, bf16 sliced output
//          X[t][g][b][48] (g = scan block, 48 = r|z|n x 16 cols).
// Phase 2: persistent 32-block x 512-thread scan. Block g owns h-cols
//          [g*16,(g+1)*16). W_h slice bf16 LDS-resident (wave-linear frag
//          layout, conflict-free). Per step: MFMA h[128][512]@Wh_slice,
//          fp32 epilogue (h carry in registers), bf16 h exchange via global
//          double buffer + per-block release-flag barrier. X[t+1] prefetched
//          across the barrier; out_seq written after the flag release.
//
// d_ws: [hA 128K][hB 128K][flags 512B][X 402,653,184 B]

#define B_DIM 128
#define S_DIM 1024
#define I_DIM 256
#define H_DIM 512
#define G_DIM 1536
#define NBLK 32
#define SLICE 16
#define SL3 48

typedef __bf16 bf16x8 __attribute__((ext_vector_type(8)));
typedef float floatx4 __attribute__((ext_vector_type(4)));

static __device__ __forceinline__ float bf2f(unsigned short u) {
    union { unsigned int i; float f; } v;
    v.i = ((unsigned int)u) << 16;
    return v.f;
}

static __device__ __forceinline__ unsigned short f2bf(float f) {
    union { float f; unsigned int i; } v;
    v.f = f;
    unsigned int lsb = (v.i >> 16) & 1;
    v.i += 0x7fffu + lsb;
    return (unsigned short)(v.i >> 16);
}

static __device__ __forceinline__ float sigmoidf_fast(float x) {
    return 1.0f / (1.0f + __expf(-x));
}
static __device__ __forceinline__ float tanhf_fast(float x) {
    return 1.0f - 2.0f / (__expf(2.0f * x) + 1.0f);
}

// ---------------------------------------------------------------------------
// Phase 1: x_proj GEMM (M=131072, K=256, N=1536), fp32, bf16 sliced output.
// ---------------------------------------------------------------------------
#define BM 64
#define BN 64
#define BK 16

__global__ __launch_bounds__(256) void xproj_gemm(
    const float* __restrict__ A,      // [131072][256]
    const float* __restrict__ W,      // [256][1536]
    const float* __restrict__ bias,   // b_in at offset 0
    unsigned short* __restrict__ X)   // sliced layout [t][32][128][48]
{
    __shared__ float As[BK][BM + 1];
    __shared__ float Bs[BK][BN];

    const int tid = threadIdx.x;
    const int tx = tid & 15;
    const int ty = tid >> 4;
    const long m0 = (long)blockIdx.x * BM;
    const int n0 = blockIdx.y * BN;

    const int arow = tid >> 2;
    const int akc = (tid & 3) * 4;
    const int bkr = tid >> 4;
    const int bnc = (tid & 15) * 4;

    float acc[4][4] = {};

    for (int k0 = 0; k0 < I_DIM; k0 += BK) {
        float4 av = *(const float4*)(A + (m0 + arow) * I_DIM + k0 + akc);
        As[akc + 0][arow] = av.x;
        As[akc + 1][arow] = av.y;
        As[akc + 2][arow] = av.z;
        As[akc + 3][arow] = av.w;
        float4 bv = *(const float4*)(W + (long)(k0 + bkr) * G_DIM + n0 + bnc);
        *(float4*)&Bs[bkr][bnc] = bv;
        __syncthreads();
#pragma unroll
        for (int k = 0; k < BK; ++k) {
            float a0 = As[k][ty * 4 + 0];
            float a1 = As[k][ty * 4 + 1];
            float a2 = As[k][ty * 4 + 2];
            float a3 = As[k][ty * 4 + 3];
            float4 b = *(const float4*)&Bs[k][tx * 4];
            acc[0][0] += a0 * b.x; acc[0][1] += a0 * b.y; acc[0][2] += a0 * b.z; acc[0][3] += a0 * b.w;
            acc[1][0] += a1 * b.x; acc[1][1] += a1 * b.y; acc[1][2] += a1 * b.z; acc[1][3] += a1 * b.w;
            acc[2][0] += a2 * b.x; acc[2][1] += a2 * b.y; acc[2][2] += a2 * b.z; acc[2][3] += a2 * b.w;
            acc[3][0] += a3 * b.x; acc[3][1] += a3 * b.y; acc[3][2] += a3 * b.z; acc[3][3] += a3 * b.w;
        }
        __syncthreads();
    }

    const int n = n0 + tx * 4;
    const int q = n >> 9;             // gate 0/1/2
    const int hc = n & 511;
    const int g = hc >> 4;            // scan block slice
    const int c = hc & 15;            // col within slice
    const float b0v = bias[n + 0];
    const float b1v = bias[n + 1];
    const float b2v = bias[n + 2];
    const float b3v = bias[n + 3];
#pragma unroll
    for (int i = 0; i < 4; ++i) {
        const long m = m0 + ty * 4 + i;
        const int b = (int)(m >> 10);
        const int t = (int)(m & 1023);
        ushort4 o;
        o.x = f2bf(acc[i][0] + b0v);
        o.y = f2bf(acc[i][1] + b1v);
        o.z = f2bf(acc[i][2] + b2v);
        o.w = f2bf(acc[i][3] + b3v);
        size_t addr = (((size_t)t * NBLK + g) * B_DIM + b) * SL3 + q * SLICE + c;
        *(ushort4*)(X + addr) = o;
    }
}

// ---------------------------------------------------------------------------
// Phase 2: persistent MFMA scan. 32 blocks x 512 threads (8 waves).
// Wave w owns M-tile w (batch rows 16w..16w+16).
// ---------------------------------------------------------------------------
__global__ __launch_bounds__(512) void gru_scan_mfma(
    const float* __restrict__ Wh,         // [512][1536]
    const float* __restrict__ bias,       // b_h at +1536
    const unsigned short* __restrict__ X, // [t][32][128][48] bf16
    unsigned short* __restrict__ hA,      // [128][512] bf16 (zeroed)
    unsigned short* __restrict__ hB,      // [128][512] bf16
    int* __restrict__ flags,              // 32 flags, 16B apart (zeroed)
    float* __restrict__ out_seq,          // [128][1024][512]
    float* __restrict__ out_last)         // [128][512]
{
    // Wave-linear B-fragment store: WtS[gate][k0i][lane][8] bf16.
    // Each ds_read_b128 is a contiguous 1KB wave access -> conflict-free.
    __shared__ __align__(16) unsigned short WtS[3 * 16 * 512];

    const int tid  = threadIdx.x;
    const int g    = blockIdx.x;
    const int lane = tid & 63;
    const int wav  = tid >> 6;        // 0..7 = M-tile
    const int c    = lane & 15;
    const int quad = lane >> 4;

    // ---- one-time: W_h slice -> LDS in fragment order ----
    for (int i = tid; i < H_DIM * SL3; i += 512) {
        int k    = i / SL3;
        int gc   = i - k * SL3;
        int gate = gc >> 4;
        int cc   = gc & 15;
        float w  = Wh[(size_t)k * G_DIM + gate * H_DIM + g * SLICE + cc];
        int k0i  = k >> 5;
        int q    = (k >> 3) & 3;
        int j    = k & 7;
        WtS[gate * 8192 + k0i * 512 + (q * 16 + cc) * 8 + j] = f2bf(w);
    }
    __syncthreads();

    const float bhr = bias[G_DIM + 0 * H_DIM + g * SLICE + c];
    const float bhz = bias[G_DIM + 1 * H_DIM + g * SLICE + c];
    const float bhn = bias[G_DIM + 2 * H_DIM + g * SLICE + c];

    const int arow = wav * 16 + c;          // A-fragment row (batch row)
    int erow[4];                            // epilogue rows (C-layout)
#pragma unroll
    for (int r = 0; r < 4; ++r) erow[r] = wav * 16 + quad * 4 + r;

    float hp[4] = {0.f, 0.f, 0.f, 0.f};    // fp32 h carry (lane-exclusive)

    // ---- prefetch X for t=0 ----
    unsigned short xr[4], xz[4], xn[4];
    {
        const unsigned short* xp = X + (size_t)g * (B_DIM * SL3);
#pragma unroll
        for (int r = 0; r < 4; ++r) {
            xr[r] = xp[erow[r] * SL3 + 0 * SLICE + c];
            xz[r] = xp[erow[r] * SL3 + 1 * SLICE + c];
            xn[r] = xp[erow[r] * SL3 + 2 * SLICE + c];
        }
    }

    for (int t = 0; t < S_DIM; ++t) {
        const unsigned short* __restrict__ hr = (t & 1) ? hB : hA;
        unsigned short* __restrict__       hw = (t & 1) ? hA : hB;

        // ---- preload all 16 A-fragments (independent IC loads) ----
        bf16x8 afr[16];
#pragma unroll
        for (int i = 0; i < 16; ++i)
            afr[i] = *(const bf16x8*)(hr + (size_t)arow * H_DIM + i * 32 + quad * 8);

        // ---- MFMA K-loop ----
        floatx4 aR = {0.f, 0.f, 0.f, 0.f}, aZ = aR, aN = aR;
        const unsigned short* wp = &WtS[lane * 8];
#pragma unroll
        for (int i = 0; i < 16; ++i) {
            bf16x8 bR = *(const bf16x8*)(wp + 0 * 8192 + i * 512);
            bf16x8 bZ = *(const bf16x8*)(wp + 1 * 8192 + i * 512);
            bf16x8 bN = *(const bf16x8*)(wp + 2 * 8192 + i * 512);
            aR = __builtin_amdgcn_mfma_f32_16x16x32_bf16(afr[i], bR, aR, 0, 0, 0);
            aZ = __builtin_amdgcn_mfma_f32_16x16x32_bf16(afr[i], bZ, aZ, 0, 0, 0);
            aN = __builtin_amdgcn_mfma_f32_16x16x32_bf16(afr[i], bN, aN, 0, 0, 0);
        }

        // ---- gate math (fp32), write h_next (critical path) ----
        float hn[4];
#pragma unroll
        for (int r = 0; r < 4; ++r) {
            const float rr = sigmoidf_fast(bf2f(xr[r]) + aR[r] + bhr);
            const float zz = sigmoidf_fast(bf2f(xz[r]) + aZ[r] + bhz);
            const float nn = tanhf_fast(bf2f(xn[r]) + rr * (aN[r] + bhn));
            hn[r] = (1.0f - zz) * nn + zz * hp[r];
            hp[r] = hn[r];
            hw[(size_t)erow[r] * H_DIM + g * SLICE + c] = f2bf(hn[r]);
        }

        if (t == S_DIM - 1) {
#pragma unroll
            for (int r = 0; r < 4; ++r) {
                out_seq[(size_t)erow[r] * (S_DIM * H_DIM) + (size_t)t * H_DIM + g * SLICE + c] = hn[r];
                out_last[(size_t)erow[r] * H_DIM + g * SLICE + c] = hn[r];
            }
            break;
        }

        // ---- release: make h_write visible, then flag ----
        __builtin_amdgcn_fence(__ATOMIC_RELEASE, "agent");
        __syncthreads();
        if (tid == 0)
            __hip_atomic_store(&flags[g * 4], t + 1, __ATOMIC_RELAXED,
                               __HIP_MEMORY_SCOPE_AGENT);

        // ---- off critical path: out_seq writes + X[t+1] prefetch ----
#pragma unroll
        for (int r = 0; r < 4; ++r)
            out_seq[(size_t)erow[r] * (S_DIM * H_DIM) + (size_t)t * H_DIM + g * SLICE + c] = hn[r];
        {
            const unsigned short* xp = X + ((size_t)(t + 1) * NBLK + g) * (B_DIM * SL3);
#pragma unroll
            for (int r = 0; r < 4; ++r) {
                xr[r] = xp[erow[r] * SL3 + 0 * SLICE + c];
                xz[r] = xp[erow[r] * SL3 + 1 * SLICE + c];
                xn[r] = xp[erow[r] * SL3 + 2 * SLICE + c];
            }
        }

        // ---- spin: wave 0 polls all 32 flags ----
        if (tid < 64) {
            const int need = t + 1;
            int ok;
            do {
                int v = (lane < NBLK)
                    ? __hip_atomic_load(&flags[lane * 4], __ATOMIC_RELAXED,
                                        __HIP_MEMORY_SCOPE_AGENT)
                    : need;
                ok = __all(v >= need);
            } while (!ok);
        }
        __syncthreads();
        __builtin_amdgcn_fence(__ATOMIC_ACQUIRE, "agent");
    }
}

extern "C" void kernel_launch(void* const* d_in, const int* in_sizes, int n_in,
                              void* d_out, int out_size, void* d_ws, size_t ws_size,
                              hipStream_t stream) {
    const float* inputs = (const float*)d_in[0];
    const float* W_in   = (const float*)d_in[1];
    const float* W_h    = (const float*)d_in[2];
    const float* bias   = (const float*)d_in[3];

    float* out_seq  = (float*)d_out;
    float* out_last = (float*)d_out + (size_t)B_DIM * S_DIM * H_DIM;

    char* ws = (char*)d_ws;
    unsigned short* hA    = (unsigned short*)ws;                 // 131072 B
    unsigned short* hB    = (unsigned short*)(ws + 131072);      // 131072 B
    int*            flags = (int*)(ws + 262144);                 // 512 B (32 x 16B)
    unsigned short* X     = (unsigned short*)(ws + 262656);      // 402,653,184 B

    hipMemsetAsync(hA, 0, 131072, stream);
    hipMemsetAsync(flags, 0, 512, stream);

    dim3 g1(B_DIM * S_DIM / BM, G_DIM / BN);
    xproj_gemm<<<g1, 256, 0, stream>>>(inputs, W_in, bias, X);

    gru_scan_mfma<<<NBLK, 512, 0, stream>>>(W_h, bias, X, hA, hB, flags,
                                            out_seq, out_last);
}